// Round 12
// baseline (422.810 us; speedup 1.0000x reference)
//
#include <hip/hip_runtime.h>

typedef unsigned short u16;
typedef unsigned int u32;
typedef __attribute__((ext_vector_type(8))) short short8;
typedef __attribute__((ext_vector_type(4))) float f32x4;

#define N_IT 80000
#define SLOT 10240000

__device__ __forceinline__ float wred(float v) {
#pragma unroll
    for (int s = 32; s; s >>= 1) v += __shfl_xor(v, s);
    return v;
}
__device__ __forceinline__ float sigf(float x) { return 1.f / (1.f + expf(-x)); }
__device__ __forceinline__ u16 f2bf(float f) {          // RNE f32->bf16
    u32 x = __float_as_uint(f);
    u32 r = x + 0x7fffu + ((x >> 16) & 1u);
    return (u16)(r >> 16);
}
__device__ __forceinline__ float bf2f(u16 v) {
    return __uint_as_float(((u32)v) << 16);
}
__device__ __forceinline__ u32 pack2(float lo, float hi) {
    return ((u32)f2bf(hi) << 16) | f2bf(lo);
}
__device__ __forceinline__ f32x4 mfma16(short8 a, short8 b, f32x4 c) {
    return __builtin_amdgcn_mfma_f32_16x16x32_bf16(a, b, c, 0, 0, 0);
}
// xor-swizzle within 32-lane half (BitMode): pattern = (xor<<10)|0x1F
#define SWZ(v, pat) __int_as_float(__builtin_amdgcn_ds_swizzle(__float_as_int(v), pat))
__device__ __forceinline__ float red16(float t) {   // sum over 16-lane group
    t += SWZ(t, 0x041F);
    t += SWZ(t, 0x081F);
    t += SWZ(t, 0x101F);
    t += SWZ(t, 0x201F);
    return t;
}
__device__ __forceinline__ float red32(float t) {   // sum over 32-lane group
    t += SWZ(t, 0x041F);
    t += SWZ(t, 0x081F);
    t += SWZ(t, 0x101F);
    t += SWZ(t, 0x201F);
    t += SWZ(t, 0x401F);
    return t;
}
__device__ __forceinline__ float red16max(float t) { // max over 16-lane group
    t = fmaxf(t, SWZ(t, 0x041F));
    t = fmaxf(t, SWZ(t, 0x081F));
    t = fmaxf(t, SWZ(t, 0x101F));
    t = fmaxf(t, SWZ(t, 0x201F));
    return t;
}
__device__ __forceinline__ float dot4(float4 a, float4 b) {
    return a.x * b.x + a.y * b.y + a.z * b.z + a.w * b.w;
}
// unpack uint4 (8 packed bf16, memory order) -> two float4
__device__ __forceinline__ void unp8(uint4 w, float4& a, float4& b) {
    a.x = __uint_as_float(w.x << 16); a.y = __uint_as_float(w.x & 0xFFFF0000u);
    a.z = __uint_as_float(w.y << 16); a.w = __uint_as_float(w.y & 0xFFFF0000u);
    b.x = __uint_as_float(w.z << 16); b.y = __uint_as_float(w.z & 0xFFFF0000u);
    b.z = __uint_as_float(w.w << 16); b.w = __uint_as_float(w.w & 0xFFFF0000u);
}
// unpack uint2 (4 packed bf16) -> float4
__device__ __forceinline__ void unp4(uint2 w, float4& a) {
    a.x = __uint_as_float(w.x << 16); a.y = __uint_as_float(w.x & 0xFFFF0000u);
    a.z = __uint_as_float(w.y << 16); a.w = __uint_as_float(w.y & 0xFFFF0000u);
}

// ---------- fused: weight converts (blocks 0..463) + row L2-norm (rest) ----------
__global__ __launch_bounds__(256) void k_cvtnorm(const float* __restrict__ Wih,
                                                 const float* __restrict__ W1,
                                                 const float* __restrict__ W2,
                                                 const float* __restrict__ Whh,
                                                 u16* __restrict__ wihbf,
                                                 u16* __restrict__ w1bf,
                                                 u16* __restrict__ w2bf,
                                                 u16* __restrict__ whhbf,
                                                 const float* __restrict__ x,
                                                 u32* __restrict__ xn) {
    if (blockIdx.x < 464) {
        int i = blockIdx.x * 256 + threadIdx.x;
        if (i < 49152) {
            wihbf[i] = f2bf(Wih[i]);
        } else if (i < 65536) {
            int j = i - 49152;
            w1bf[j] = f2bf(W1[j]);
        } else if (i < 69632) {
            int j = i - 65536;              // w2bf [32][128], rows>=20 zero
            int row = j >> 7, col = j & 127;
            w2bf[j] = (row < 20) ? f2bf(W2[row * 128 + col]) : (u16)0;
        } else if (i < 118784) {
            int j = i - 69632;
            whhbf[j] = f2bf(Whh[j]);
        }
        return;
    }
    int wid = ((blockIdx.x - 464) * 256 + threadIdx.x) >> 6;
    int l = threadIdx.x & 63;
    size_t base = (size_t)wid * 128;
    float2 v = *(const float2*)(x + base + 2 * l);
    float s = wred(v.x * v.x + v.y * v.y);
    float r = 1.f / sqrtf(s + 1e-12f);
    xn[(size_t)wid * 64 + l] = pack2(v.x * r, v.y * r);
}

// ---------- hop-1 routing: 32 lanes/item, 4 dims/lane, 2 items/wave ----------
// Register diet (z = 12 x uint2 = 24 VGPR, total demand ~65) to fit hipcc's
// (256,3) budget of 84 VGPRs. R2/R8 lesson: demand > 84 at (256,3) spills the
// z-block (WRITE_SIZE 380+ MB, 2.5x slower). Go/no-go check: WRITE_SIZE ~20 MB.
__global__ __launch_bounds__(256, 3) void k_routeb(const u32* __restrict__ xn,
                                                   const int* __restrict__ adj,
                                                   u32* __restrict__ out) {
    int tid = blockIdx.x * 256 + threadIdx.x;
    int item = tid >> 5;
    int sl = threadIdx.x & 31;
    float4 x0;
    unp4(*(const uint2*)(xn + (size_t)item * 64 + sl * 2), x0);
    const int4* ar = (const int4*)(adj + (size_t)(item + 1) * 12);
    int4 a0 = ar[0], a1 = ar[1], a2 = ar[2];
    uint2 zw[12];
#define LDZ(i, comp) zw[i] = *(const uint2*)(xn + (size_t)((comp) - 1) * 64 + sl * 2);
    LDZ(0, a0.x) LDZ(1, a0.y) LDZ(2, a0.z) LDZ(3, a0.w)
    LDZ(4, a1.x) LDZ(5, a1.y) LDZ(6, a1.z) LDZ(7, a1.w)
    LDZ(8, a2.x) LDZ(9, a2.y) LDZ(10, a2.z) LDZ(11, a2.w)
#undef LDZ
    float4 u = x0;
#pragma unroll
    for (int it = 0; it < 4; it++) {
        float p[12]; float sum = 0.f;
#pragma unroll
        for (int m = 0; m < 12; m++) {
            float4 z; unp4(zw[m], z);
            float t = red32(dot4(u, z));
            p[m] = __expf(t);           // |t|<=1 (unit vectors): no max-sub needed
            sum += p[m];
        }
        float inv = 1.f / sum;
        u = x0;
#pragma unroll
        for (int m = 0; m < 12; m++) {
            float pm = p[m] * inv;
            float4 z; unp4(zw[m], z);
            u.x += pm * z.x; u.y += pm * z.y; u.z += pm * z.z; u.w += pm * z.w;
        }
        float nn = red32(dot4(u, u));
        float rr = 1.f / sqrtf(nn + 1e-12f);
        u.x *= rr; u.y *= rr; u.z *= rr; u.w *= rr;
    }
    *(uint2*)(out + (size_t)item * 64 + sl * 2) =
        make_uint2(pack2(u.x, u.y), pack2(u.z, u.w));
}

// ---------- hop-2 routing (32 lanes/item) FUSED with LN1 -> ivbf ----------
__global__ __launch_bounds__(256, 3) void k_route2lnb(const u32* __restrict__ xn,
                                                      const float* __restrict__ emb,
                                                      const int* __restrict__ adj,
                                                      const float* __restrict__ g,
                                                      const float* __restrict__ bb,
                                                      u32* __restrict__ ivbf) {
    int tid = blockIdx.x * 256 + threadIdx.x;
    int item = tid >> 5;
    int sl = threadIdx.x & 31;
    float4 x0;
    unp4(*(const uint2*)(xn + (size_t)item * 64 + sl * 2), x0);
    const int4* ar = (const int4*)(adj + (size_t)(item + 1) * 12);
    int4 a0 = ar[0], a1 = ar[1], a2 = ar[2];
    uint2 zw[12];
#define LDZ(i, comp) zw[i] = *(const uint2*)(xn + (size_t)((comp) - 1) * 64 + sl * 2);
    LDZ(0, a0.x) LDZ(1, a0.y) LDZ(2, a0.z) LDZ(3, a0.w)
    LDZ(4, a1.x) LDZ(5, a1.y) LDZ(6, a1.z) LDZ(7, a1.w)
    LDZ(8, a2.x) LDZ(9, a2.y) LDZ(10, a2.z) LDZ(11, a2.w)
#undef LDZ
    float4 u = x0;
#pragma unroll
    for (int it = 0; it < 4; it++) {
        float p[12]; float sum = 0.f;
#pragma unroll
        for (int m = 0; m < 12; m++) {
            float4 z; unp4(zw[m], z);
            float t = red32(dot4(u, z));
            p[m] = __expf(t);
            sum += p[m];
        }
        float inv = 1.f / sum;
        u = x0;
#pragma unroll
        for (int m = 0; m < 12; m++) {
            float pm = p[m] * inv;
            float4 z; unp4(zw[m], z);
            u.x += pm * z.x; u.y += pm * z.y; u.z += pm * z.z; u.w += pm * z.w;
        }
        float nn = red32(dot4(u, u));
        float rr = 1.f / sqrtf(nn + 1e-12f);
        u.x *= rr; u.y *= rr; u.z *= rr; u.w *= rr;
    }
    // acc = emb + out1(x) + out2(u);  LN over 128 dims via red32
    float4 e = *(const float4*)(emb + (size_t)item * 128 + sl * 4);
    float v0 = e.x + x0.x + u.x, v1 = e.y + x0.y + u.y;
    float v2 = e.z + x0.z + u.z, v3 = e.w + x0.w + u.w;
    float s = red32(v0 + v1 + v2 + v3);
    float q = red32(v0 * v0 + v1 * v1 + v2 * v2 + v3 * v3);
    float mean = s * (1.f / 128.f);
    float var = q * (1.f / 128.f) - mean * mean;
    float r = 1.f / sqrtf(var + 1e-5f);
    float4 gg = *(const float4*)(g + sl * 4);
    float4 bg = *(const float4*)(bb + sl * 4);
    float y0 = (v0 - mean) * r * gg.x + bg.x;
    float y1 = (v1 - mean) * r * gg.y + bg.y;
    float y2 = (v2 - mean) * r * gg.z + bg.z;
    float y3 = (v3 - mean) * r * gg.w + bg.w;
    // row stride = 64 u32 (128 bf16) -- item*32 was the R4/R5 corruption bug
    *(uint2*)(ivbf + (size_t)item * 64 + sl * 2) =
        make_uint2(pack2(y0, y1), pack2(y2, y3));
}

// ---------- fused MLP -> pop softmax -> @anchors -> LN2 -> pvbf ----------
// 4 waves/block, 16 items/wave; anchors staged to LDS (k_prep folded in).
__global__ __launch_bounds__(256, 2) void k_popm(const u16* __restrict__ ivbf,
                                                 const u16* __restrict__ w1bf,
                                                 const float* __restrict__ b1,
                                                 const u16* __restrict__ w2bf,
                                                 const float* __restrict__ b2,
                                                 const float* __restrict__ tau,
                                                 const int* __restrict__ anchors,
                                                 const float* __restrict__ g2,
                                                 const float* __restrict__ bb2,
                                                 u16* __restrict__ pvbf) {
    __shared__ u16 buf[4][16][136];          // per-wave scratch (h / P overlay)
    __shared__ u16 anchS[128][40];           // [d][class], pad->16B-aligned rows
    int tid = threadIdx.x;
    for (int e = tid; e < 4096; e += 256) {
        int d = e >> 5, k = e & 31;
        anchS[d][k] = (k < 20) ? ivbf[(size_t)(anchors[k] - 1) * 128 + d] : (u16)0;
    }
    __syncthreads();
    int w = tid >> 6, l = tid & 63;
    int g16 = l >> 4, c = l & 15;
    int item0 = blockIdx.x * 64 + w * 16;
    const u16* ap = ivbf + (size_t)(item0 + c) * 128 + g16 * 8;
    short8 A[4];
#pragma unroll
    for (int kb = 0; kb < 4; kb++) A[kb] = *(const short8*)(ap + kb * 32);
    // stage 1: h = leaky(iv @ W1^T + b1), bf16, transposed into LDS
#pragma unroll
    for (int nt = 0; nt < 8; nt++) {
        const u16* wp = w1bf + (nt * 16 + c) * 128 + g16 * 8;
        f32x4 acc = {0.f, 0.f, 0.f, 0.f};
#pragma unroll
        for (int kb = 0; kb < 4; kb++)
            acc = mfma16(A[kb], *(const short8*)(wp + kb * 32), acc);
        float bias = b1[nt * 16 + c];
#pragma unroll
        for (int qq = 0; qq < 4; qq++) {
            float hv = acc[qq] + bias;
            hv = hv >= 0.f ? hv : 0.01f * hv;
            buf[w][4 * g16 + qq][nt * 16 + c] = f2bf(hv);
        }
    }
    // stage 2: logits = h @ W2^T (padded 32); softmax over classes
    short8 A2[4];
#pragma unroll
    for (int kb = 0; kb < 4; kb++)
        A2[kb] = *(const short8*)&buf[w][c][g16 * 8 + kb * 32];
    f32x4 L0 = {0.f, 0.f, 0.f, 0.f}, L1 = {0.f, 0.f, 0.f, 0.f};
#pragma unroll
    for (int kb = 0; kb < 4; kb++) {
        L0 = mfma16(A2[kb], *(const short8*)(w2bf + c * 128 + g16 * 8 + kb * 32), L0);
        L1 = mfma16(A2[kb], *(const short8*)(w2bf + (16 + c) * 128 + g16 * 8 + kb * 32), L1);
    }
    float it = 1.f / tau[0];
    float b2v0 = b2[c];
    float b2v1 = (c < 4) ? b2[16 + c] : 0.f;
#pragma unroll
    for (int qq = 0; qq < 4; qq++) {
        float v0 = (L0[qq] + b2v0) * it;
        float v1 = (c < 4) ? (L1[qq] + b2v1) * it : -1e30f;
        float mx = red16max(fmaxf(v0, v1));
        float e0 = __expf(v0 - mx);
        float e1 = (c < 4) ? __expf(v1 - mx) : 0.f;
        float ssum = red16(e0 + e1);
        float inv = 1.f / ssum;
        buf[w][4 * g16 + qq][c] = f2bf(e0 * inv);
        buf[w][4 * g16 + qq][16 + c] = f2bf(e1 * inv);
    }
    // stage 3: pv = P @ anchors_emb, then LN2
    short8 A3 = *(const short8*)&buf[w][c][g16 * 8];
    f32x4 pv[8];
#pragma unroll
    for (int nt = 0; nt < 8; nt++) {
        const short8 B3 = *(const short8*)&anchS[nt * 16 + c][g16 * 8];
        f32x4 zz = {0.f, 0.f, 0.f, 0.f};
        pv[nt] = mfma16(A3, B3, zz);
    }
    float g2v[8], b2gv[8];
#pragma unroll
    for (int t = 0; t < 8; t++) { g2v[t] = g2[t * 16 + c]; b2gv[t] = bb2[t * 16 + c]; }
#pragma unroll
    for (int qq = 0; qq < 4; qq++) {
        float ps = 0.f, psq = 0.f;
#pragma unroll
        for (int t = 0; t < 8; t++) { float x = pv[t][qq]; ps += x; psq += x * x; }
        float s = red16(ps), sq = red16(psq);
        float mean = s * (1.f / 128.f);
        float var = sq * (1.f / 128.f) - mean * mean;
        float r = 1.f / sqrtf(var + 1e-5f);
        size_t base = (size_t)(item0 + 4 * g16 + qq) * 128;
#pragma unroll
        for (int t = 0; t < 8; t++) {
            float y = (pv[t][qq] - mean) * r * g2v[t] + b2gv[t];
            pvbf[base + t * 16 + c] = f2bf(y);
        }
    }
}

// ---------- gi_all[512*50][384] = gather(iv/pv)[sess] @ W_ih^T + b_ih (bf16 out) ----------
__global__ __launch_bounds__(256) void k_gi(const int* __restrict__ sess,
                                            const u16* __restrict__ ivbf,
                                            const u16* __restrict__ pvbf,
                                            const u16* __restrict__ wbf,
                                            const float* __restrict__ bih,
                                            u16* __restrict__ gi) {
    int w = threadIdx.x >> 6, l = threadIdx.x & 63;
    int mt = blockIdx.x * 4 + w;
    int r = mt * 16 + (l & 15);
    int s = r / 50, t = r - s * 50;
    int idx = sess[(s & 255) * 50 + t];
    const u16* srcb = (s < 256) ? ivbf : pvbf;
    int ko = (l >> 4) * 8;
    const short8 Z8 = {0, 0, 0, 0, 0, 0, 0, 0};
    short8 A[4];
    if (idx == 0) {
#pragma unroll
        for (int kb = 0; kb < 4; kb++) A[kb] = Z8;
    } else {
        const u16* rp = srcb + (size_t)(idx - 1) * 128 + ko;
#pragma unroll
        for (int kb = 0; kb < 4; kb++) A[kb] = *(const short8*)(rp + kb * 32);
    }
    int rowb = mt * 16 + (l >> 4) * 4;
    for (int nt = 0; nt < 24; nt++) {
        int gcol = nt * 16 + (l & 15);
        const u16* wp = wbf + gcol * 128 + ko;
        f32x4 acc = {0.f, 0.f, 0.f, 0.f};
#pragma unroll
        for (int kb = 0; kb < 4; kb++)
            acc = mfma16(A[kb], *(const short8*)(wp + kb * 32), acc);
        float bias = bih[gcol];
#pragma unroll
        for (int q = 0; q < 4; q++)
            gi[(size_t)(rowb + q) * 384 + gcol] = f2bf(acc[q] + bias);
    }
}

// ---------- GRU: 256 blocks x 2 seqs (b, b+256 share lengths[b]); W_hh bf16 in
// LDS. R9 lesson: hipcc won't keep a 128-VGPR weight array resident -> L2
// re-stream, 31 TB/s, 159 us. R10 lesson: MFMA version = 32 blocks = 12.5% of
// CUs + unprefetched per-step gi loads -> 186 us. This version: all 256 CUs,
// weights read from LDS (swizzled, at the 8-dword/bank structural floor), gi
// prefetched one step ahead.
__global__ __launch_bounds__(384, 1) void k_gru(const u16* __restrict__ gibf,
                                                const u16* __restrict__ whhbf,
                                                const float* __restrict__ bhh,
                                                const int* __restrict__ lengths,
                                                const float* __restrict__ g3,
                                                const float* __restrict__ b3,
                                                const float* __restrict__ g4,
                                                const float* __restrict__ b4,
                                                u32* __restrict__ htbf) {
    __shared__ u16 whhS[49152];                  // 96 KB, row-swizzled
    __shared__ __align__(16) float hA[2][128], hB[2][128];
    __shared__ float rA[128], zA[128], hnA[128], inA[128];
    __shared__ float rB[128], zB[128], hnB[128], inB[128];
    int g = threadIdx.x, b = blockIdx.x;
    // stage W_hh bf16 -> LDS, swizzle idx ^= ((row&15)<<3) (same XOR on read)
    for (int e8 = g * 8; e8 < 49152; e8 += 3072) {
        uint4 v = *(const uint4*)&whhbf[e8];
        *(uint4*)&whhS[e8 ^ (((e8 >> 7) & 15) << 3)] = v;
    }
    float bh = bhh[g];
    if (g < 128) { hA[0][g] = 0.f; hB[0][g] = 0.f; }
    int len = lengths[b];
    const u16* giA = gibf + (size_t)b * 50 * 384 + g;
    const u16* giB = gibf + (size_t)(b + 256) * 50 * 384 + g;
    int xo = (g & 15) << 3;
    const u16* wrow = &whhS[g * 128];
    float ga = bf2f(giA[0]), gb = bf2f(giB[0]);   // prefetch t=0
    __syncthreads();
    int par = 0;
    for (int t = 0; t < len; t++) {
        // prefetch next step's gi (hidden under the dot-product chain)
        float ga_n = 0.f, gb_n = 0.f;
        if (t + 1 < len) {
            ga_n = bf2f(giA[(t + 1) * 384]);
            gb_n = bf2f(giB[(t + 1) * 384]);
        }
        float aA = bh, aB = bh;
#pragma unroll
        for (int k = 0; k < 16; k++) {
            uint4 wv = *(const uint4*)&wrow[(k * 8) ^ xo];
            float4 w0, w1; unp8(wv, w0, w1);
            const float4* hap = (const float4*)&hA[par][k * 8];
            const float4* hbp = (const float4*)&hB[par][k * 8];
            float4 ha0 = hap[0], ha1 = hap[1];
            float4 hb0 = hbp[0], hb1 = hbp[1];
            aA += dot4(w0, ha0) + dot4(w1, ha1);
            aB += dot4(w0, hb0) + dot4(w1, hb1);
        }
        if (g < 128) {
            rA[g] = 1.f / (1.f + __expf(-(ga + aA)));
            rB[g] = 1.f / (1.f + __expf(-(gb + aB)));
        } else if (g < 256) {
            zA[g - 128] = 1.f / (1.f + __expf(-(ga + aA)));
            zB[g - 128] = 1.f / (1.f + __expf(-(gb + aB)));
        } else {
            inA[g - 256] = ga; hnA[g - 256] = aA;
            inB[g - 256] = gb; hnB[g - 256] = aB;
        }
        __syncthreads();
        if (g < 128) {
            float narg = inA[g] + rA[g] * hnA[g];
            float e2 = __expf(2.f * narg);
            float n = 1.f - 2.f / (e2 + 1.f);    // tanh, saturation-safe
            hA[par ^ 1][g] = (1.f - zA[g]) * n + zA[g] * hA[par][g];
        } else if (g < 256) {
            int d = g - 128;
            float narg = inB[d] + rB[d] * hnB[d];
            float e2 = __expf(2.f * narg);
            float n = 1.f - 2.f / (e2 + 1.f);
            hB[par ^ 1][d] = (1.f - zB[d]) * n + zB[d] * hB[par][d];
        }
        __syncthreads();
        par ^= 1; ga = ga_n; gb = gb_n;
    }
    int w = g >> 6, l = g & 63;
    if (w == 0) {
        float2 v = *(const float2*)&hA[par][2 * l];
        float s = wred(v.x + v.y), q = wred(v.x * v.x + v.y * v.y);
        float mean = s * (1.f / 128.f), var = q * (1.f / 128.f) - mean * mean;
        float r = 1.f / sqrtf(var + 1e-5f);
        float2 gg = *(const float2*)(g3 + 2 * l), bg = *(const float2*)(b3 + 2 * l);
        float y0 = (v.x - mean) * r * gg.x + bg.x;
        float y1 = (v.y - mean) * r * gg.y + bg.y;
        htbf[(size_t)b * 64 + l] = pack2(y0, y1);
    } else if (w == 1) {
        float2 v = *(const float2*)&hB[par][2 * l];
        float s = wred(v.x + v.y), q = wred(v.x * v.x + v.y * v.y);
        float mean = s * (1.f / 128.f), var = q * (1.f / 128.f) - mean * mean;
        float r = 1.f / sqrtf(var + 1e-5f);
        float2 gg = *(const float2*)(g4 + 2 * l), bg = *(const float2*)(b4 + 2 * l);
        float y0 = (v.x - mean) * r * gg.x + bg.x;
        float y1 = (v.y - mean) * r * gg.y + bg.y;
        htbf[(size_t)(b + 256) * 64 + l] = pack2(y0, y1);
    }
}

// ---------- scores: BM=256(all) x BN=64/block, bf16 MFMA, 3 outputs ----------
__global__ __launch_bounds__(256) void k_scores(const u16* __restrict__ htbf,
                                                const u16* __restrict__ ivbf,
                                                const u16* __restrict__ pvbf,
                                                const float* __restrict__ a1,
                                                const float* __restrict__ a2,
                                                float* __restrict__ out) {
    int w = threadIdx.x >> 6, l = threadIdx.x & 63;
    int n0 = blockIdx.x * 64;
    int ko = (l >> 4) * 8;
    short8 Ai[4][4], Ap[4][4];
#pragma unroll
    for (int mi = 0; mi < 4; mi++) {
        int row = w * 64 + mi * 16 + (l & 15);
        const u16* pi = htbf + row * 128 + ko;
        const u16* pp = htbf + (row + 256) * 128 + ko;
#pragma unroll
        for (int kb = 0; kb < 4; kb++) {
            Ai[mi][kb] = *(const short8*)(pi + kb * 32);
            Ap[mi][kb] = *(const short8*)(pp + kb * 32);
        }
    }
    float s1 = sigf(a1[0]), s2 = sigf(a2[0]);
    float* sc = out;
    float* si = out + (size_t)20480000;
    float* sp = out + (size_t)40960000;
    for (int nt = 0; nt < 4; nt++) {
        int col = n0 + nt * 16 + (l & 15);
        const u16* bi = ivbf + (size_t)col * 128 + ko;
        const u16* bp = pvbf + (size_t)col * 128 + ko;
        short8 Bi[4], Bp[4];
#pragma unroll
        for (int kb = 0; kb < 4; kb++) {
            Bi[kb] = *(const short8*)(bi + kb * 32);
            Bp[kb] = *(const short8*)(bp + kb * 32);
        }
#pragma unroll
        for (int mi = 0; mi < 4; mi++) {
            f32x4 ai = {0.f, 0.f, 0.f, 0.f}, ap = {0.f, 0.f, 0.f, 0.f};
#pragma unroll
            for (int kb = 0; kb < 4; kb++) {
                ai = mfma16(Ai[mi][kb], Bi[kb], ai);
                ap = mfma16(Ap[mi][kb], Bp[kb], ap);
            }
            int rowb = w * 64 + mi * 16 + (l >> 4) * 4;
#pragma unroll
            for (int q = 0; q < 4; q++) {
                size_t o = (size_t)(rowb + q) * 80000 + col;
                float vi = ai[q], vp = ap[q];
                __builtin_nontemporal_store(vi, si + o);
                __builtin_nontemporal_store(vp, sp + o);
                __builtin_nontemporal_store(s1 * vi + s2 * vp, sc + o);
            }
        }
    }
}

extern "C" void kernel_launch(void* const* d_in, const int* in_sizes, int n_in,
                              void* d_out, int out_size, void* d_ws, size_t ws_size,
                              hipStream_t stream) {
    (void)in_sizes; (void)n_in; (void)out_size; (void)ws_size;
    const int*   sess    = (const int*)d_in[0];
    const int*   lengths = (const int*)d_in[1];
    const float* tau     = (const float*)d_in[4];
    const int*   adj     = (const int*)d_in[5];
    const int*   anchors = (const int*)d_in[6];
    const float* emb     = (const float*)d_in[7];
    const float* W_ih    = (const float*)d_in[8];
    const float* W_hh    = (const float*)d_in[9];
    const float* b_ih    = (const float*)d_in[10];
    const float* b_hh    = (const float*)d_in[11];
    const float* W1      = (const float*)d_in[12];
    const float* b1      = (const float*)d_in[13];
    const float* W2      = (const float*)d_in[14];
    const float* b2      = (const float*)d_in[15];
    const float* a1      = (const float*)d_in[16];
    const float* a2      = (const float*)d_in[17];
    const float* ln1g = (const float*)d_in[18];
    const float* ln1b = (const float*)d_in[19];
    const float* ln2g = (const float*)d_in[20];
    const float* ln2b = (const float*)d_in[21];
    const float* ln3g = (const float*)d_in[22];
    const float* ln3b = (const float*)d_in[23];
    const float* ln4g = (const float*)d_in[24];
    const float* ln4b = (const float*)d_in[25];

    float* out = (float*)d_out;
    // d_out doubles as scratch; all scratch dead before k_scores overwrites it.
    u32* o_xn = (u32*)out;                   // packed bf16 xn (5.12M u32)
    u32* o_o1 = (u32*)(out + SLOT);          // packed bf16 hop-1 out
    u16* o_gi = (u16*)(out + 2 * SLOT);      // gi_all bf16 (9.83M u16)

    u16* ws16   = (u16*)d_ws;        // ~41.4 MB
    u16* ivbf   = ws16;                      // 10,240,000
    u16* pvbf   = ws16 + 10240000;           // 10,240,000
    u16* wihbf  = ws16 + 20480000;           // 49,152
    u16* htbf   = ws16 + 20529152;           // 65,536
    u16* w1bf   = ws16 + 20594688;           // 16,384
    u16* w2bf   = ws16 + 20611072;           // 4,096
    u16* whhbf  = ws16 + 20615168;           // 49,152

    k_cvtnorm<<<20464, 256, 0, stream>>>(W_ih, W1, W2, W_hh, wihbf, w1bf, w2bf,
                                         whhbf, emb + 128, o_xn);
    k_routeb<<<10000, 256, 0, stream>>>(o_xn, adj, o_o1);
    k_route2lnb<<<10000, 256, 0, stream>>>(o_o1, emb + 128, adj, ln1g, ln1b, (u32*)ivbf);
    k_popm<<<1250, 256, 0, stream>>>(ivbf, w1bf, b1, w2bf, b2, tau, anchors,
                                     ln2g, ln2b, pvbf);
    k_gi<<<400, 256, 0, stream>>>(sess, ivbf, pvbf, wihbf, b_ih, o_gi);
    k_gru<<<256, 384, 0, stream>>>(o_gi, whhbf, b_hh, lengths, ln3g, ln3b, ln4g, ln4b,
                                   (u32*)htbf);
    k_scores<<<1250, 256, 0, stream>>>(htbf, ivbf, pvbf, a1, a2, out);
}

// Round 13
// 381.486 us; speedup vs baseline: 1.1083x; 1.1083x over previous
//
#include <hip/hip_runtime.h>

typedef unsigned short u16;
typedef unsigned int u32;
typedef __attribute__((ext_vector_type(8))) short short8;
typedef __attribute__((ext_vector_type(4))) float f32x4;

#define N_IT 80000
#define SLOT 10240000

__device__ __forceinline__ float wred(float v) {
#pragma unroll
    for (int s = 32; s; s >>= 1) v += __shfl_xor(v, s);
    return v;
}
__device__ __forceinline__ float sigf(float x) { return 1.f / (1.f + expf(-x)); }
__device__ __forceinline__ u16 f2bf(float f) {          // RNE f32->bf16
    u32 x = __float_as_uint(f);
    u32 r = x + 0x7fffu + ((x >> 16) & 1u);
    return (u16)(r >> 16);
}
__device__ __forceinline__ float bf2f(u16 v) {
    return __uint_as_float(((u32)v) << 16);
}
__device__ __forceinline__ u32 pack2(float lo, float hi) {
    return ((u32)f2bf(hi) << 16) | f2bf(lo);
}
__device__ __forceinline__ f32x4 mfma16(short8 a, short8 b, f32x4 c) {
    return __builtin_amdgcn_mfma_f32_16x16x32_bf16(a, b, c, 0, 0, 0);
}
// DPP cross-lane (VALU pipe, ~2-4 cyc vs ~35 for ds_swizzle). 16-lane
// reduction = quad_perm(xor1) 0xB1, quad_perm(xor2) 0x4E, row_half_mirror
// 0x141 (8-group), row_mirror 0x140 (16-group). R12 lesson: the serialized
// ds_swizzle chains were the routes' latency floor, not occupancy.
template <int CTRL>
__device__ __forceinline__ float dppmv(float v) {
    return __int_as_float(
        __builtin_amdgcn_update_dpp(0, __float_as_int(v), CTRL, 0xF, 0xF, true));
}
__device__ __forceinline__ float red16(float t) {   // sum over 16-lane group
    t += dppmv<0xB1>(t);
    t += dppmv<0x4E>(t);
    t += dppmv<0x141>(t);
    t += dppmv<0x140>(t);
    return t;
}
__device__ __forceinline__ float red16max(float t) { // max over 16-lane group
    t = fmaxf(t, dppmv<0xB1>(t));
    t = fmaxf(t, dppmv<0x4E>(t));
    t = fmaxf(t, dppmv<0x141>(t));
    t = fmaxf(t, dppmv<0x140>(t));
    return t;
}
__device__ __forceinline__ float dot4(float4 a, float4 b) {
    return a.x * b.x + a.y * b.y + a.z * b.z + a.w * b.w;
}
// unpack uint4 (8 packed bf16, memory order) -> two float4
__device__ __forceinline__ void unp8(uint4 w, float4& a, float4& b) {
    a.x = __uint_as_float(w.x << 16); a.y = __uint_as_float(w.x & 0xFFFF0000u);
    a.z = __uint_as_float(w.y << 16); a.w = __uint_as_float(w.y & 0xFFFF0000u);
    b.x = __uint_as_float(w.z << 16); b.y = __uint_as_float(w.z & 0xFFFF0000u);
    b.z = __uint_as_float(w.w << 16); b.w = __uint_as_float(w.w & 0xFFFF0000u);
}

// ---------- fused: weight converts (blocks 0..463) + row L2-norm (rest) ----------
__global__ __launch_bounds__(256) void k_cvtnorm(const float* __restrict__ Wih,
                                                 const float* __restrict__ W1,
                                                 const float* __restrict__ W2,
                                                 const float* __restrict__ Whh,
                                                 u16* __restrict__ wihbf,
                                                 u16* __restrict__ w1bf,
                                                 u16* __restrict__ w2bf,
                                                 u16* __restrict__ whhbf,
                                                 const float* __restrict__ x,
                                                 u32* __restrict__ xn) {
    if (blockIdx.x < 464) {
        int i = blockIdx.x * 256 + threadIdx.x;
        if (i < 49152) {
            wihbf[i] = f2bf(Wih[i]);
        } else if (i < 65536) {
            int j = i - 49152;
            w1bf[j] = f2bf(W1[j]);
        } else if (i < 69632) {
            int j = i - 65536;              // w2bf [32][128], rows>=20 zero
            int row = j >> 7, col = j & 127;
            w2bf[j] = (row < 20) ? f2bf(W2[row * 128 + col]) : (u16)0;
        } else if (i < 118784) {
            int j = i - 69632;
            whhbf[j] = f2bf(Whh[j]);
        }
        return;
    }
    int wid = ((blockIdx.x - 464) * 256 + threadIdx.x) >> 6;
    int l = threadIdx.x & 63;
    size_t base = (size_t)wid * 128;
    float2 v = *(const float2*)(x + base + 2 * l);
    float s = wred(v.x * v.x + v.y * v.y);
    float r = 1.f / sqrtf(s + 1e-12f);
    xn[(size_t)wid * 64 + l] = pack2(v.x * r, v.y * r);
}

// ---------- hop-1 routing, packed-z, 16 lanes/item ----------
// (256,2) ONLY: launch_bounds(256,3) makes hipcc allocate exactly 84 VGPRs and
// spill the z-block to scratch (observed R2 AND R8: WRITE_SIZE 380-410 MB, ~2.5x
// slower). Do not raise the waves/EU bound on this kernel.
__global__ __launch_bounds__(256, 2) void k_routeb(const u32* __restrict__ xn,
                                                   const int* __restrict__ adj,
                                                   u32* __restrict__ out) {
    int tid = blockIdx.x * 256 + threadIdx.x;
    int item = tid >> 4;
    int sl = threadIdx.x & 15;
    float4 x0, x1;
    unp8(*(const uint4*)(xn + (size_t)item * 64 + sl * 4), x0, x1);
    const int4* ar = (const int4*)(adj + (size_t)(item + 1) * 12);
    int4 a0 = ar[0], a1 = ar[1], a2 = ar[2];
    uint4 zw[12];
#define LDZ(i, comp) zw[i] = *(const uint4*)(xn + (size_t)((comp) - 1) * 64 + sl * 4);
    LDZ(0, a0.x) LDZ(1, a0.y) LDZ(2, a0.z) LDZ(3, a0.w)
    LDZ(4, a1.x) LDZ(5, a1.y) LDZ(6, a1.z) LDZ(7, a1.w)
    LDZ(8, a2.x) LDZ(9, a2.y) LDZ(10, a2.z) LDZ(11, a2.w)
#undef LDZ
    float4 u0 = x0, u1 = x1;
#pragma unroll
    for (int it = 0; it < 4; it++) {
        float p[12]; float sum = 0.f;
#pragma unroll
        for (int m = 0; m < 12; m++) {
            float4 a, b; unp8(zw[m], a, b);
            float t = dot4(u0, a) + dot4(u1, b);
            t = red16(t);
            p[m] = __expf(t);           // |t|<=1 (unit vectors): no max-sub needed
            sum += p[m];
        }
        float inv = 1.f / sum;
        u0 = x0; u1 = x1;
#pragma unroll
        for (int m = 0; m < 12; m++) {
            float pm = p[m] * inv;
            float4 a, b; unp8(zw[m], a, b);
            u0.x += pm * a.x; u0.y += pm * a.y; u0.z += pm * a.z; u0.w += pm * a.w;
            u1.x += pm * b.x; u1.y += pm * b.y; u1.z += pm * b.z; u1.w += pm * b.w;
        }
        float nn = red16(dot4(u0, u0) + dot4(u1, u1));
        float rr = 1.f / sqrtf(nn + 1e-12f);
        u0.x *= rr; u0.y *= rr; u0.z *= rr; u0.w *= rr;
        u1.x *= rr; u1.y *= rr; u1.z *= rr; u1.w *= rr;
    }
    uint4 o = make_uint4(pack2(u0.x, u0.y), pack2(u0.z, u0.w),
                         pack2(u1.x, u1.y), pack2(u1.z, u1.w));
    *(uint4*)(out + (size_t)item * 64 + sl * 4) = o;
}

// ---------- hop-2 routing (packed-z) FUSED with LN1 -> ivbf ----------
// (256,2) ONLY -- see k_routeb spill note.
__global__ __launch_bounds__(256, 2) void k_route2lnb(const u32* __restrict__ xn,
                                                      const float* __restrict__ emb,
                                                      const int* __restrict__ adj,
                                                      const float* __restrict__ g,
                                                      const float* __restrict__ bb,
                                                      u32* __restrict__ ivbf) {
    int tid = blockIdx.x * 256 + threadIdx.x;
    int item = tid >> 4;
    int sl = threadIdx.x & 15;
    float4 x0, x1;
    unp8(*(const uint4*)(xn + (size_t)item * 64 + sl * 4), x0, x1);
    const int4* ar = (const int4*)(adj + (size_t)(item + 1) * 12);
    int4 a0 = ar[0], a1 = ar[1], a2 = ar[2];
    uint4 zw[12];
#define LDZ(i, comp) zw[i] = *(const uint4*)(xn + (size_t)((comp) - 1) * 64 + sl * 4);
    LDZ(0, a0.x) LDZ(1, a0.y) LDZ(2, a0.z) LDZ(3, a0.w)
    LDZ(4, a1.x) LDZ(5, a1.y) LDZ(6, a1.z) LDZ(7, a1.w)
    LDZ(8, a2.x) LDZ(9, a2.y) LDZ(10, a2.z) LDZ(11, a2.w)
#undef LDZ
    float4 u0 = x0, u1 = x1;
#pragma unroll
    for (int it = 0; it < 4; it++) {
        float p[12]; float sum = 0.f;
#pragma unroll
        for (int m = 0; m < 12; m++) {
            float4 a, b; unp8(zw[m], a, b);
            float t = dot4(u0, a) + dot4(u1, b);
            t = red16(t);
            p[m] = __expf(t);
            sum += p[m];
        }
        float inv = 1.f / sum;
        u0 = x0; u1 = x1;
#pragma unroll
        for (int m = 0; m < 12; m++) {
            float pm = p[m] * inv;
            float4 a, b; unp8(zw[m], a, b);
            u0.x += pm * a.x; u0.y += pm * a.y; u0.z += pm * a.z; u0.w += pm * a.w;
            u1.x += pm * b.x; u1.y += pm * b.y; u1.z += pm * b.z; u1.w += pm * b.w;
        }
        float nn = red16(dot4(u0, u0) + dot4(u1, u1));
        float rr = 1.f / sqrtf(nn + 1e-12f);
        u0.x *= rr; u0.y *= rr; u0.z *= rr; u0.w *= rr;
        u1.x *= rr; u1.y *= rr; u1.z *= rr; u1.w *= rr;
    }
    // acc = emb + out1(x) + out2(u);  LN over 128 dims via red16
    const float4* er = (const float4*)(emb + (size_t)item * 128 + sl * 8);
    float4 e0 = er[0], e1 = er[1];
    float v[8];
    v[0] = e0.x + x0.x + u0.x; v[1] = e0.y + x0.y + u0.y;
    v[2] = e0.z + x0.z + u0.z; v[3] = e0.w + x0.w + u0.w;
    v[4] = e1.x + x1.x + u1.x; v[5] = e1.y + x1.y + u1.y;
    v[6] = e1.z + x1.z + u1.z; v[7] = e1.w + x1.w + u1.w;
    float s = 0.f, q = 0.f;
#pragma unroll
    for (int j = 0; j < 8; j++) { s += v[j]; q += v[j] * v[j]; }
    s = red16(s); q = red16(q);
    float mean = s * (1.f / 128.f);
    float var = q * (1.f / 128.f) - mean * mean;
    float r = 1.f / sqrtf(var + 1e-5f);
    const float4* gr = (const float4*)(g + sl * 8);
    const float4* br = (const float4*)(bb + sl * 8);
    float4 g0 = gr[0], g1 = gr[1], bw0 = br[0], bw1 = br[1];
    float y[8];
    y[0] = (v[0] - mean) * r * g0.x + bw0.x; y[1] = (v[1] - mean) * r * g0.y + bw0.y;
    y[2] = (v[2] - mean) * r * g0.z + bw0.z; y[3] = (v[3] - mean) * r * g0.w + bw0.w;
    y[4] = (v[4] - mean) * r * g1.x + bw1.x; y[5] = (v[5] - mean) * r * g1.y + bw1.y;
    y[6] = (v[6] - mean) * r * g1.z + bw1.z; y[7] = (v[7] - mean) * r * g1.w + bw1.w;
    // row stride = 64 u32 (128 bf16) -- item*32 was the R4/R5 corruption bug
    uint4 o = make_uint4(pack2(y[0], y[1]), pack2(y[2], y[3]),
                         pack2(y[4], y[5]), pack2(y[6], y[7]));
    *(uint4*)(ivbf + (size_t)item * 64 + sl * 4) = o;
}

// ---------- fused MLP -> pop softmax -> @anchors -> LN2 -> pvbf ----------
// 4 waves/block, 16 items/wave; anchors staged to LDS (k_prep folded in).
__global__ __launch_bounds__(256, 2) void k_popm(const u16* __restrict__ ivbf,
                                                 const u16* __restrict__ w1bf,
                                                 const float* __restrict__ b1,
                                                 const u16* __restrict__ w2bf,
                                                 const float* __restrict__ b2,
                                                 const float* __restrict__ tau,
                                                 const int* __restrict__ anchors,
                                                 const float* __restrict__ g2,
                                                 const float* __restrict__ bb2,
                                                 u16* __restrict__ pvbf) {
    __shared__ u16 buf[4][16][136];          // per-wave scratch (h / P overlay)
    __shared__ u16 anchS[128][40];           // [d][class], pad->16B-aligned rows
    int tid = threadIdx.x;
    for (int e = tid; e < 4096; e += 256) {
        int d = e >> 5, k = e & 31;
        anchS[d][k] = (k < 20) ? ivbf[(size_t)(anchors[k] - 1) * 128 + d] : (u16)0;
    }
    __syncthreads();
    int w = tid >> 6, l = tid & 63;
    int g16 = l >> 4, c = l & 15;
    int item0 = blockIdx.x * 64 + w * 16;
    const u16* ap = ivbf + (size_t)(item0 + c) * 128 + g16 * 8;
    short8 A[4];
#pragma unroll
    for (int kb = 0; kb < 4; kb++) A[kb] = *(const short8*)(ap + kb * 32);
    // stage 1: h = leaky(iv @ W1^T + b1), bf16, transposed into LDS
#pragma unroll
    for (int nt = 0; nt < 8; nt++) {
        const u16* wp = w1bf + (nt * 16 + c) * 128 + g16 * 8;
        f32x4 acc = {0.f, 0.f, 0.f, 0.f};
#pragma unroll
        for (int kb = 0; kb < 4; kb++)
            acc = mfma16(A[kb], *(const short8*)(wp + kb * 32), acc);
        float bias = b1[nt * 16 + c];
#pragma unroll
        for (int qq = 0; qq < 4; qq++) {
            float hv = acc[qq] + bias;
            hv = hv >= 0.f ? hv : 0.01f * hv;
            buf[w][4 * g16 + qq][nt * 16 + c] = f2bf(hv);
        }
    }
    // stage 2: logits = h @ W2^T (padded 32); softmax over classes
    short8 A2[4];
#pragma unroll
    for (int kb = 0; kb < 4; kb++)
        A2[kb] = *(const short8*)&buf[w][c][g16 * 8 + kb * 32];
    f32x4 L0 = {0.f, 0.f, 0.f, 0.f}, L1 = {0.f, 0.f, 0.f, 0.f};
#pragma unroll
    for (int kb = 0; kb < 4; kb++) {
        L0 = mfma16(A2[kb], *(const short8*)(w2bf + c * 128 + g16 * 8 + kb * 32), L0);
        L1 = mfma16(A2[kb], *(const short8*)(w2bf + (16 + c) * 128 + g16 * 8 + kb * 32), L1);
    }
    float it = 1.f / tau[0];
    float b2v0 = b2[c];
    float b2v1 = (c < 4) ? b2[16 + c] : 0.f;
#pragma unroll
    for (int qq = 0; qq < 4; qq++) {
        float v0 = (L0[qq] + b2v0) * it;
        float v1 = (c < 4) ? (L1[qq] + b2v1) * it : -1e30f;
        float mx = red16max(fmaxf(v0, v1));
        float e0 = __expf(v0 - mx);
        float e1 = (c < 4) ? __expf(v1 - mx) : 0.f;
        float ssum = red16(e0 + e1);
        float inv = 1.f / ssum;
        buf[w][4 * g16 + qq][c] = f2bf(e0 * inv);
        buf[w][4 * g16 + qq][16 + c] = f2bf(e1 * inv);
    }
    // stage 3: pv = P @ anchors_emb, then LN2
    short8 A3 = *(const short8*)&buf[w][c][g16 * 8];
    f32x4 pv[8];
#pragma unroll
    for (int nt = 0; nt < 8; nt++) {
        const short8 B3 = *(const short8*)&anchS[nt * 16 + c][g16 * 8];
        f32x4 zz = {0.f, 0.f, 0.f, 0.f};
        pv[nt] = mfma16(A3, B3, zz);
    }
    float g2v[8], b2gv[8];
#pragma unroll
    for (int t = 0; t < 8; t++) { g2v[t] = g2[t * 16 + c]; b2gv[t] = bb2[t * 16 + c]; }
#pragma unroll
    for (int qq = 0; qq < 4; qq++) {
        float ps = 0.f, psq = 0.f;
#pragma unroll
        for (int t = 0; t < 8; t++) { float x = pv[t][qq]; ps += x; psq += x * x; }
        float s = red16(ps), sq = red16(psq);
        float mean = s * (1.f / 128.f);
        float var = sq * (1.f / 128.f) - mean * mean;
        float r = 1.f / sqrtf(var + 1e-5f);
        size_t base = (size_t)(item0 + 4 * g16 + qq) * 128;
#pragma unroll
        for (int t = 0; t < 8; t++) {
            float y = (pv[t][qq] - mean) * r * g2v[t] + b2gv[t];
            pvbf[base + t * 16 + c] = f2bf(y);
        }
    }
}

// ---------- gi_all[512*50][384] = gather(iv/pv)[sess] @ W_ih^T + b_ih (bf16 out) ----------
__global__ __launch_bounds__(256) void k_gi(const int* __restrict__ sess,
                                            const u16* __restrict__ ivbf,
                                            const u16* __restrict__ pvbf,
                                            const u16* __restrict__ wbf,
                                            const float* __restrict__ bih,
                                            u16* __restrict__ gi) {
    int w = threadIdx.x >> 6, l = threadIdx.x & 63;
    int mt = blockIdx.x * 4 + w;
    int r = mt * 16 + (l & 15);
    int s = r / 50, t = r - s * 50;
    int idx = sess[(s & 255) * 50 + t];
    const u16* srcb = (s < 256) ? ivbf : pvbf;
    int ko = (l >> 4) * 8;
    const short8 Z8 = {0, 0, 0, 0, 0, 0, 0, 0};
    short8 A[4];
    if (idx == 0) {
#pragma unroll
        for (int kb = 0; kb < 4; kb++) A[kb] = Z8;
    } else {
        const u16* rp = srcb + (size_t)(idx - 1) * 128 + ko;
#pragma unroll
        for (int kb = 0; kb < 4; kb++) A[kb] = *(const short8*)(rp + kb * 32);
    }
    int rowb = mt * 16 + (l >> 4) * 4;
    for (int nt = 0; nt < 24; nt++) {
        int gcol = nt * 16 + (l & 15);
        const u16* wp = wbf + gcol * 128 + ko;
        f32x4 acc = {0.f, 0.f, 0.f, 0.f};
#pragma unroll
        for (int kb = 0; kb < 4; kb++)
            acc = mfma16(A[kb], *(const short8*)(wp + kb * 32), acc);
        float bias = bih[gcol];
#pragma unroll
        for (int q = 0; q < 4; q++)
            gi[(size_t)(rowb + q) * 384 + gcol] = f2bf(acc[q] + bias);
    }
}

// ---------- GRU: 256 blocks x 2 seqs (b, b+256 share lengths[b]); W_hh bf16 in
// LDS. R9 lesson: hipcc won't keep a 128-VGPR weight array resident -> L2
// re-stream, 31 TB/s, 159 us. R10 lesson: MFMA version = 32 blocks = 12.5% of
// CUs + unprefetched per-step gi loads -> 186 us. This version: all 256 CUs,
// weights read from LDS (swizzled, at the 8-dword/bank structural floor), gi
// prefetched one step ahead.
__global__ __launch_bounds__(384, 1) void k_gru(const u16* __restrict__ gibf,
                                                const u16* __restrict__ whhbf,
                                                const float* __restrict__ bhh,
                                                const int* __restrict__ lengths,
                                                const float* __restrict__ g3,
                                                const float* __restrict__ b3,
                                                const float* __restrict__ g4,
                                                const float* __restrict__ b4,
                                                u32* __restrict__ htbf) {
    __shared__ u16 whhS[49152];                  // 96 KB, row-swizzled
    __shared__ __align__(16) float hA[2][128], hB[2][128];
    __shared__ float rA[128], zA[128], hnA[128], inA[128];
    __shared__ float rB[128], zB[128], hnB[128], inB[128];
    int g = threadIdx.x, b = blockIdx.x;
    // stage W_hh bf16 -> LDS, swizzle idx ^= ((row&15)<<3) (same XOR on read)
    for (int e8 = g * 8; e8 < 49152; e8 += 3072) {
        uint4 v = *(const uint4*)&whhbf[e8];
        *(uint4*)&whhS[e8 ^ (((e8 >> 7) & 15) << 3)] = v;
    }
    float bh = bhh[g];
    if (g < 128) { hA[0][g] = 0.f; hB[0][g] = 0.f; }
    int len = lengths[b];
    const u16* giA = gibf + (size_t)b * 50 * 384 + g;
    const u16* giB = gibf + (size_t)(b + 256) * 50 * 384 + g;
    int xo = (g & 15) << 3;
    const u16* wrow = &whhS[g * 128];
    float ga = bf2f(giA[0]), gb = bf2f(giB[0]);   // prefetch t=0
    __syncthreads();
    int par = 0;
    for (int t = 0; t < len; t++) {
        // prefetch next step's gi (hidden under the dot-product chain)
        float ga_n = 0.f, gb_n = 0.f;
        if (t + 1 < len) {
            ga_n = bf2f(giA[(t + 1) * 384]);
            gb_n = bf2f(giB[(t + 1) * 384]);
        }
        float aA = bh, aB = bh;
#pragma unroll
        for (int k = 0; k < 16; k++) {
            uint4 wv = *(const uint4*)&wrow[(k * 8) ^ xo];
            float4 w0, w1; unp8(wv, w0, w1);
            const float4* hap = (const float4*)&hA[par][k * 8];
            const float4* hbp = (const float4*)&hB[par][k * 8];
            float4 ha0 = hap[0], ha1 = hap[1];
            float4 hb0 = hbp[0], hb1 = hbp[1];
            aA += dot4(w0, ha0) + dot4(w1, ha1);
            aB += dot4(w0, hb0) + dot4(w1, hb1);
        }
        if (g < 128) {
            rA[g] = 1.f / (1.f + __expf(-(ga + aA)));
            rB[g] = 1.f / (1.f + __expf(-(gb + aB)));
        } else if (g < 256) {
            zA[g - 128] = 1.f / (1.f + __expf(-(ga + aA)));
            zB[g - 128] = 1.f / (1.f + __expf(-(gb + aB)));
        } else {
            inA[g - 256] = ga; hnA[g - 256] = aA;
            inB[g - 256] = gb; hnB[g - 256] = aB;
        }
        __syncthreads();
        if (g < 128) {
            float narg = inA[g] + rA[g] * hnA[g];
            float e2 = __expf(2.f * narg);
            float n = 1.f - 2.f / (e2 + 1.f);    // tanh, saturation-safe
            hA[par ^ 1][g] = (1.f - zA[g]) * n + zA[g] * hA[par][g];
        } else if (g < 256) {
            int d = g - 128;
            float narg = inB[d] + rB[d] * hnB[d];
            float e2 = __expf(2.f * narg);
            float n = 1.f - 2.f / (e2 + 1.f);
            hB[par ^ 1][d] = (1.f - zB[d]) * n + zB[d] * hB[par][d];
        }
        __syncthreads();
        par ^= 1; ga = ga_n; gb = gb_n;
    }
    int w = g >> 6, l = g & 63;
    if (w == 0) {
        float2 v = *(const float2*)&hA[par][2 * l];
        float s = wred(v.x + v.y), q = wred(v.x * v.x + v.y * v.y);
        float mean = s * (1.f / 128.f), var = q * (1.f / 128.f) - mean * mean;
        float r = 1.f / sqrtf(var + 1e-5f);
        float2 gg = *(const float2*)(g3 + 2 * l), bg = *(const float2*)(b3 + 2 * l);
        float y0 = (v.x - mean) * r * gg.x + bg.x;
        float y1 = (v.y - mean) * r * gg.y + bg.y;
        htbf[(size_t)b * 64 + l] = pack2(y0, y1);
    } else if (w == 1) {
        float2 v = *(const float2*)&hB[par][2 * l];
        float s = wred(v.x + v.y), q = wred(v.x * v.x + v.y * v.y);
        float mean = s * (1.f / 128.f), var = q * (1.f / 128.f) - mean * mean;
        float r = 1.f / sqrtf(var + 1e-5f);
        float2 gg = *(const float2*)(g4 + 2 * l), bg = *(const float2*)(b4 + 2 * l);
        float y0 = (v.x - mean) * r * gg.x + bg.x;
        float y1 = (v.y - mean) * r * gg.y + bg.y;
        htbf[(size_t)(b + 256) * 64 + l] = pack2(y0, y1);
    }
}

// ---------- scores: BM=256(all) x BN=64/block, bf16 MFMA, 3 outputs ----------
__global__ __launch_bounds__(256) void k_scores(const u16* __restrict__ htbf,
                                                const u16* __restrict__ ivbf,
                                                const u16* __restrict__ pvbf,
                                                const float* __restrict__ a1,
                                                const float* __restrict__ a2,
                                                float* __restrict__ out) {
    int w = threadIdx.x >> 6, l = threadIdx.x & 63;
    int n0 = blockIdx.x * 64;
    int ko = (l >> 4) * 8;
    short8 Ai[4][4], Ap[4][4];
#pragma unroll
    for (int mi = 0; mi < 4; mi++) {
        int row = w * 64 + mi * 16 + (l & 15);
        const u16* pi = htbf + row * 128 + ko;
        const u16* pp = htbf + (row + 256) * 128 + ko;
#pragma unroll
        for (int kb = 0; kb < 4; kb++) {
            Ai[mi][kb] = *(const short8*)(pi + kb * 32);
            Ap[mi][kb] = *(const short8*)(pp + kb * 32);
        }
    }
    float s1 = sigf(a1[0]), s2 = sigf(a2[0]);
    float* sc = out;
    float* si = out + (size_t)20480000;
    float* sp = out + (size_t)40960000;
    for (int nt = 0; nt < 4; nt++) {
        int col = n0 + nt * 16 + (l & 15);
        const u16* bi = ivbf + (size_t)col * 128 + ko;
        const u16* bp = pvbf + (size_t)col * 128 + ko;
        short8 Bi[4], Bp[4];
#pragma unroll
        for (int kb = 0; kb < 4; kb++) {
            Bi[kb] = *(const short8*)(bi + kb * 32);
            Bp[kb] = *(const short8*)(bp + kb * 32);
        }
#pragma unroll
        for (int mi = 0; mi < 4; mi++) {
            f32x4 ai = {0.f, 0.f, 0.f, 0.f}, ap = {0.f, 0.f, 0.f, 0.f};
#pragma unroll
            for (int kb = 0; kb < 4; kb++) {
                ai = mfma16(Ai[mi][kb], Bi[kb], ai);
                ap = mfma16(Ap[mi][kb], Bp[kb], ap);
            }
            int rowb = w * 64 + mi * 16 + (l >> 4) * 4;
#pragma unroll
            for (int q = 0; q < 4; q++) {
                size_t o = (size_t)(rowb + q) * 80000 + col;
                float vi = ai[q], vp = ap[q];
                __builtin_nontemporal_store(vi, si + o);
                __builtin_nontemporal_store(vp, sp + o);
                __builtin_nontemporal_store(s1 * vi + s2 * vp, sc + o);
            }
        }
    }
}

extern "C" void kernel_launch(void* const* d_in, const int* in_sizes, int n_in,
                              void* d_out, int out_size, void* d_ws, size_t ws_size,
                              hipStream_t stream) {
    (void)in_sizes; (void)n_in; (void)out_size; (void)ws_size;
    const int*   sess    = (const int*)d_in[0];
    const int*   lengths = (const int*)d_in[1];
    const float* tau     = (const float*)d_in[4];
    const int*   adj     = (const int*)d_in[5];
    const int*   anchors = (const int*)d_in[6];
    const float* emb     = (const float*)d_in[7];
    const float* W_ih    = (const float*)d_in[8];
    const float* W_hh    = (const float*)d_in[9];
    const float* b_ih    = (const float*)d_in[10];
    const float* b_hh    = (const float*)d_in[11];
    const float* W1      = (const float*)d_in[12];
    const float* b1      = (const float*)d_in[13];
    const float* W2      = (const float*)d_in[14];
    const float* b2      = (const float*)d_in[15];
    const float* a1      = (const float*)d_in[16];
    const float* a2      = (const float*)d_in[17];
    const float* ln1g = (const float*)d_in[18];
    const float* ln1b = (const float*)d_in[19];
    const float* ln2g = (const float*)d_in[20];
    const float* ln2b = (const float*)d_in[21];
    const float* ln3g = (const float*)d_in[22];
    const float* ln3b = (const float*)d_in[23];
    const float* ln4g = (const float*)d_in[24];
    const float* ln4b = (const float*)d_in[25];

    float* out = (float*)d_out;
    // d_out doubles as scratch; all scratch dead before k_scores overwrites it.
    u32* o_xn = (u32*)out;                   // packed bf16 xn (5.12M u32)
    u32* o_o1 = (u32*)(out + SLOT);          // packed bf16 hop-1 out
    u16* o_gi = (u16*)(out + 2 * SLOT);      // gi_all bf16 (9.83M u16)

    u16* ws16   = (u16*)d_ws;        // ~41.4 MB
    u16* ivbf   = ws16;                      // 10,240,000
    u16* pvbf   = ws16 + 10240000;           // 10,240,000
    u16* wihbf  = ws16 + 20480000;           // 49,152
    u16* htbf   = ws16 + 20529152;           // 65,536
    u16* w1bf   = ws16 + 20594688;           // 16,384
    u16* w2bf   = ws16 + 20611072;           // 4,096
    u16* whhbf  = ws16 + 20615168;           // 49,152

    k_cvtnorm<<<20464, 256, 0, stream>>>(W_ih, W1, W2, W_hh, wihbf, w1bf, w2bf,
                                         whhbf, emb + 128, o_xn);
    k_routeb<<<5000, 256, 0, stream>>>(o_xn, adj, o_o1);
    k_route2lnb<<<5000, 256, 0, stream>>>(o_o1, emb + 128, adj, ln1g, ln1b, (u32*)ivbf);
    k_popm<<<1250, 256, 0, stream>>>(ivbf, w1bf, b1, w2bf, b2, tau, anchors,
                                     ln2g, ln2b, pvbf);
    k_gi<<<400, 256, 0, stream>>>(sess, ivbf, pvbf, wihbf, b_ih, o_gi);
    k_gru<<<256, 384, 0, stream>>>(o_gi, whhbf, b_hh, lengths, ln3g, ln3b, ln4g, ln4b,
                                   (u32*)htbf);
    k_scores<<<1250, 256, 0, stream>>>(htbf, ivbf, pvbf, a1, a2, out);
}

// Round 14
// 379.371 us; speedup vs baseline: 1.1145x; 1.0056x over previous
//
#include <hip/hip_runtime.h>

typedef unsigned short u16;
typedef unsigned int u32;
typedef __attribute__((ext_vector_type(8))) short short8;
typedef __attribute__((ext_vector_type(4))) float f32x4;

#define N_IT 80000
#define SLOT 10240000

__device__ __forceinline__ float sigf(float x) { return 1.f / (1.f + expf(-x)); }
__device__ __forceinline__ u16 f2bf(float f) {          // RNE f32->bf16
    u32 x = __float_as_uint(f);
    u32 r = x + 0x7fffu + ((x >> 16) & 1u);
    return (u16)(r >> 16);
}
__device__ __forceinline__ float bf2f(u16 v) {
    return __uint_as_float(((u32)v) << 16);
}
__device__ __forceinline__ u32 pack2(float lo, float hi) {
    return ((u32)f2bf(hi) << 16) | f2bf(lo);
}
__device__ __forceinline__ f32x4 mfma16(short8 a, short8 b, f32x4 c) {
    return __builtin_amdgcn_mfma_f32_16x16x32_bf16(a, b, c, 0, 0, 0);
}
// DPP cross-lane (VALU pipe, ~2-4 cyc vs ~35 for ds_swizzle). 16-lane
// reduction = quad_perm(xor1) 0xB1, quad_perm(xor2) 0x4E, row_half_mirror
// 0x141 (8-group), row_mirror 0x140 (16-group). R13: ds_swizzle->DPP was -32us.
template <int CTRL>
__device__ __forceinline__ float dppmv(float v) {
    return __int_as_float(
        __builtin_amdgcn_update_dpp(0, __float_as_int(v), CTRL, 0xF, 0xF, true));
}
__device__ __forceinline__ float red16(float t) {   // sum over 16-lane group
    t += dppmv<0xB1>(t);
    t += dppmv<0x4E>(t);
    t += dppmv<0x141>(t);
    t += dppmv<0x140>(t);
    return t;
}
__device__ __forceinline__ float red16max(float t) { // max over 16-lane group
    t = fmaxf(t, dppmv<0xB1>(t));
    t = fmaxf(t, dppmv<0x4E>(t));
    t = fmaxf(t, dppmv<0x141>(t));
    t = fmaxf(t, dppmv<0x140>(t));
    return t;
}
__device__ __forceinline__ float wred(float v) {    // 64-lane sum (GRU LN only)
#pragma unroll
    for (int s = 32; s; s >>= 1) v += __shfl_xor(v, s);
    return v;
}
__device__ __forceinline__ float dot4(float4 a, float4 b) {
    return a.x * b.x + a.y * b.y + a.z * b.z + a.w * b.w;
}
// unpack uint4 (8 packed bf16, memory order) -> two float4
__device__ __forceinline__ void unp8(uint4 w, float4& a, float4& b) {
    a.x = __uint_as_float(w.x << 16); a.y = __uint_as_float(w.x & 0xFFFF0000u);
    a.z = __uint_as_float(w.y << 16); a.w = __uint_as_float(w.y & 0xFFFF0000u);
    b.x = __uint_as_float(w.z << 16); b.y = __uint_as_float(w.z & 0xFFFF0000u);
    b.z = __uint_as_float(w.w << 16); b.w = __uint_as_float(w.w & 0xFFFF0000u);
}

// ---------- fused: weight converts (blocks 0..463) + row L2-norm (rest) ----------
// Norm section: 16 lanes/row, 8 dims/lane, DPP red16 (R13/R14: DPP beats shfl).
__global__ __launch_bounds__(256) void k_cvtnorm(const float* __restrict__ Wih,
                                                 const float* __restrict__ W1,
                                                 const float* __restrict__ W2,
                                                 const float* __restrict__ Whh,
                                                 u16* __restrict__ wihbf,
                                                 u16* __restrict__ w1bf,
                                                 u16* __restrict__ w2bf,
                                                 u16* __restrict__ whhbf,
                                                 const float* __restrict__ x,
                                                 u32* __restrict__ xn) {
    if (blockIdx.x < 464) {
        int i = blockIdx.x * 256 + threadIdx.x;
        if (i < 49152) {
            wihbf[i] = f2bf(Wih[i]);
        } else if (i < 65536) {
            int j = i - 49152;
            w1bf[j] = f2bf(W1[j]);
        } else if (i < 69632) {
            int j = i - 65536;              // w2bf [32][128], rows>=20 zero
            int row = j >> 7, col = j & 127;
            w2bf[j] = (row < 20) ? f2bf(W2[row * 128 + col]) : (u16)0;
        } else if (i < 118784) {
            int j = i - 69632;
            whhbf[j] = f2bf(Whh[j]);
        }
        return;
    }
    int item = (blockIdx.x - 464) * 16 + (threadIdx.x >> 4);
    int sl = threadIdx.x & 15;
    const float4* xr = (const float4*)(x + (size_t)item * 128 + sl * 8);
    float4 a = xr[0], b = xr[1];
    float s = red16(dot4(a, a) + dot4(b, b));
    float r = 1.f / sqrtf(s + 1e-12f);
    *(uint4*)(xn + (size_t)item * 64 + sl * 4) =
        make_uint4(pack2(a.x * r, a.y * r), pack2(a.z * r, a.w * r),
                   pack2(b.x * r, b.y * r), pack2(b.z * r, b.w * r));
}

// ---------- hop-1 routing, packed-z, 16 lanes/item, fused exp-accumulate ----------
// u = x + (sum_m e_m z_m)/(sum_m e_m): accumulate e*z right after each exp --
// kills the second z-unpack pass (~16% VALU) and the p[12] array (R14).
// (256,2) ONLY: launch_bounds(256,3) makes hipcc allocate exactly 84 VGPRs and
// spill the z-block to scratch (observed R2 AND R8: WRITE_SIZE 380-410 MB).
__global__ __launch_bounds__(256, 2) void k_routeb(const u32* __restrict__ xn,
                                                   const int* __restrict__ adj,
                                                   u32* __restrict__ out) {
    int tid = blockIdx.x * 256 + threadIdx.x;
    int item = tid >> 4;
    int sl = threadIdx.x & 15;
    float4 x0, x1;
    unp8(*(const uint4*)(xn + (size_t)item * 64 + sl * 4), x0, x1);
    const int4* ar = (const int4*)(adj + (size_t)(item + 1) * 12);
    int4 a0 = ar[0], a1 = ar[1], a2 = ar[2];
    uint4 zw[12];
#define LDZ(i, comp) zw[i] = *(const uint4*)(xn + (size_t)((comp) - 1) * 64 + sl * 4);
    LDZ(0, a0.x) LDZ(1, a0.y) LDZ(2, a0.z) LDZ(3, a0.w)
    LDZ(4, a1.x) LDZ(5, a1.y) LDZ(6, a1.z) LDZ(7, a1.w)
    LDZ(8, a2.x) LDZ(9, a2.y) LDZ(10, a2.z) LDZ(11, a2.w)
#undef LDZ
    float4 u0 = x0, u1 = x1;
#pragma unroll
    for (int it = 0; it < 4; it++) {
        float sum = 0.f;
        float4 c0 = {0.f, 0.f, 0.f, 0.f}, c1 = {0.f, 0.f, 0.f, 0.f};
#pragma unroll
        for (int m = 0; m < 12; m++) {
            float4 a, b; unp8(zw[m], a, b);
            float t = red16(dot4(u0, a) + dot4(u1, b));
            float e = __expf(t);        // |t|<=1 (unit vectors): no max-sub needed
            sum += e;
            c0.x += e * a.x; c0.y += e * a.y; c0.z += e * a.z; c0.w += e * a.w;
            c1.x += e * b.x; c1.y += e * b.y; c1.z += e * b.z; c1.w += e * b.w;
        }
        float inv = 1.f / sum;
        u0.x = x0.x + c0.x * inv; u0.y = x0.y + c0.y * inv;
        u0.z = x0.z + c0.z * inv; u0.w = x0.w + c0.w * inv;
        u1.x = x1.x + c1.x * inv; u1.y = x1.y + c1.y * inv;
        u1.z = x1.z + c1.z * inv; u1.w = x1.w + c1.w * inv;
        float nn = red16(dot4(u0, u0) + dot4(u1, u1));
        float rr = 1.f / sqrtf(nn + 1e-12f);
        u0.x *= rr; u0.y *= rr; u0.z *= rr; u0.w *= rr;
        u1.x *= rr; u1.y *= rr; u1.z *= rr; u1.w *= rr;
    }
    uint4 o = make_uint4(pack2(u0.x, u0.y), pack2(u0.z, u0.w),
                         pack2(u1.x, u1.y), pack2(u1.z, u1.w));
    *(uint4*)(out + (size_t)item * 64 + sl * 4) = o;
}

// ---------- hop-2 routing (fused accumulate) + LN1 -> ivbf ----------
// (256,2) ONLY -- see k_routeb spill note.
__global__ __launch_bounds__(256, 2) void k_route2lnb(const u32* __restrict__ xn,
                                                      const float* __restrict__ emb,
                                                      const int* __restrict__ adj,
                                                      const float* __restrict__ g,
                                                      const float* __restrict__ bb,
                                                      u32* __restrict__ ivbf) {
    int tid = blockIdx.x * 256 + threadIdx.x;
    int item = tid >> 4;
    int sl = threadIdx.x & 15;
    float4 x0, x1;
    unp8(*(const uint4*)(xn + (size_t)item * 64 + sl * 4), x0, x1);
    const int4* ar = (const int4*)(adj + (size_t)(item + 1) * 12);
    int4 a0 = ar[0], a1 = ar[1], a2 = ar[2];
    uint4 zw[12];
#define LDZ(i, comp) zw[i] = *(const uint4*)(xn + (size_t)((comp) - 1) * 64 + sl * 4);
    LDZ(0, a0.x) LDZ(1, a0.y) LDZ(2, a0.z) LDZ(3, a0.w)
    LDZ(4, a1.x) LDZ(5, a1.y) LDZ(6, a1.z) LDZ(7, a1.w)
    LDZ(8, a2.x) LDZ(9, a2.y) LDZ(10, a2.z) LDZ(11, a2.w)
#undef LDZ
    float4 u0 = x0, u1 = x1;
#pragma unroll
    for (int it = 0; it < 4; it++) {
        float sum = 0.f;
        float4 c0 = {0.f, 0.f, 0.f, 0.f}, c1 = {0.f, 0.f, 0.f, 0.f};
#pragma unroll
        for (int m = 0; m < 12; m++) {
            float4 a, b; unp8(zw[m], a, b);
            float t = red16(dot4(u0, a) + dot4(u1, b));
            float e = __expf(t);
            sum += e;
            c0.x += e * a.x; c0.y += e * a.y; c0.z += e * a.z; c0.w += e * a.w;
            c1.x += e * b.x; c1.y += e * b.y; c1.z += e * b.z; c1.w += e * b.w;
        }
        float inv = 1.f / sum;
        u0.x = x0.x + c0.x * inv; u0.y = x0.y + c0.y * inv;
        u0.z = x0.z + c0.z * inv; u0.w = x0.w + c0.w * inv;
        u1.x = x1.x + c1.x * inv; u1.y = x1.y + c1.y * inv;
        u1.z = x1.z + c1.z * inv; u1.w = x1.w + c1.w * inv;
        float nn = red16(dot4(u0, u0) + dot4(u1, u1));
        float rr = 1.f / sqrtf(nn + 1e-12f);
        u0.x *= rr; u0.y *= rr; u0.z *= rr; u0.w *= rr;
        u1.x *= rr; u1.y *= rr; u1.z *= rr; u1.w *= rr;
    }
    // acc = emb + out1(x) + out2(u);  LN over 128 dims via red16
    const float4* er = (const float4*)(emb + (size_t)item * 128 + sl * 8);
    float4 e0 = er[0], e1 = er[1];
    float v[8];
    v[0] = e0.x + x0.x + u0.x; v[1] = e0.y + x0.y + u0.y;
    v[2] = e0.z + x0.z + u0.z; v[3] = e0.w + x0.w + u0.w;
    v[4] = e1.x + x1.x + u1.x; v[5] = e1.y + x1.y + u1.y;
    v[6] = e1.z + x1.z + u1.z; v[7] = e1.w + x1.w + u1.w;
    float s = 0.f, q = 0.f;
#pragma unroll
    for (int j = 0; j < 8; j++) { s += v[j]; q += v[j] * v[j]; }
    s = red16(s); q = red16(q);
    float mean = s * (1.f / 128.f);
    float var = q * (1.f / 128.f) - mean * mean;
    float r = 1.f / sqrtf(var + 1e-5f);
    const float4* gr = (const float4*)(g + sl * 8);
    const float4* br = (const float4*)(bb + sl * 8);
    float4 g0 = gr[0], g1 = gr[1], bw0 = br[0], bw1 = br[1];
    float y[8];
    y[0] = (v[0] - mean) * r * g0.x + bw0.x; y[1] = (v[1] - mean) * r * g0.y + bw0.y;
    y[2] = (v[2] - mean) * r * g0.z + bw0.z; y[3] = (v[3] - mean) * r * g0.w + bw0.w;
    y[4] = (v[4] - mean) * r * g1.x + bw1.x; y[5] = (v[5] - mean) * r * g1.y + bw1.y;
    y[6] = (v[6] - mean) * r * g1.z + bw1.z; y[7] = (v[7] - mean) * r * g1.w + bw1.w;
    // row stride = 64 u32 (128 bf16) -- item*32 was the R4/R5 corruption bug
    uint4 o = make_uint4(pack2(y[0], y[1]), pack2(y[2], y[3]),
                         pack2(y[4], y[5]), pack2(y[6], y[7]));
    *(uint4*)(ivbf + (size_t)item * 64 + sl * 4) = o;
}

// ---------- fused MLP -> pop softmax -> @anchors -> LN2 -> pvbf ----------
// 4 waves/block, 16 items/wave; anchors staged to LDS (k_prep folded in).
__global__ __launch_bounds__(256, 2) void k_popm(const u16* __restrict__ ivbf,
                                                 const u16* __restrict__ w1bf,
                                                 const float* __restrict__ b1,
                                                 const u16* __restrict__ w2bf,
                                                 const float* __restrict__ b2,
                                                 const float* __restrict__ tau,
                                                 const int* __restrict__ anchors,
                                                 const float* __restrict__ g2,
                                                 const float* __restrict__ bb2,
                                                 u16* __restrict__ pvbf) {
    __shared__ u16 buf[4][16][136];          // per-wave scratch (h / P overlay)
    __shared__ u16 anchS[128][40];           // [d][class], pad->16B-aligned rows
    int tid = threadIdx.x;
    for (int e = tid; e < 4096; e += 256) {
        int d = e >> 5, k = e & 31;
        anchS[d][k] = (k < 20) ? ivbf[(size_t)(anchors[k] - 1) * 128 + d] : (u16)0;
    }
    __syncthreads();
    int w = tid >> 6, l = tid & 63;
    int g16 = l >> 4, c = l & 15;
    int item0 = blockIdx.x * 64 + w * 16;
    const u16* ap = ivbf + (size_t)(item0 + c) * 128 + g16 * 8;
    short8 A[4];
#pragma unroll
    for (int kb = 0; kb < 4; kb++) A[kb] = *(const short8*)(ap + kb * 32);
    // stage 1: h = leaky(iv @ W1^T + b1), bf16, transposed into LDS
#pragma unroll
    for (int nt = 0; nt < 8; nt++) {
        const u16* wp = w1bf + (nt * 16 + c) * 128 + g16 * 8;
        f32x4 acc = {0.f, 0.f, 0.f, 0.f};
#pragma unroll
        for (int kb = 0; kb < 4; kb++)
            acc = mfma16(A[kb], *(const short8*)(wp + kb * 32), acc);
        float bias = b1[nt * 16 + c];
#pragma unroll
        for (int qq = 0; qq < 4; qq++) {
            float hv = acc[qq] + bias;
            hv = hv >= 0.f ? hv : 0.01f * hv;
            buf[w][4 * g16 + qq][nt * 16 + c] = f2bf(hv);
        }
    }
    // stage 2: logits = h @ W2^T (padded 32); softmax over classes
    short8 A2[4];
#pragma unroll
    for (int kb = 0; kb < 4; kb++)
        A2[kb] = *(const short8*)&buf[w][c][g16 * 8 + kb * 32];
    f32x4 L0 = {0.f, 0.f, 0.f, 0.f}, L1 = {0.f, 0.f, 0.f, 0.f};
#pragma unroll
    for (int kb = 0; kb < 4; kb++) {
        L0 = mfma16(A2[kb], *(const short8*)(w2bf + c * 128 + g16 * 8 + kb * 32), L0);
        L1 = mfma16(A2[kb], *(const short8*)(w2bf + (16 + c) * 128 + g16 * 8 + kb * 32), L1);
    }
    float it = 1.f / tau[0];
    float b2v0 = b2[c];
    float b2v1 = (c < 4) ? b2[16 + c] : 0.f;
#pragma unroll
    for (int qq = 0; qq < 4; qq++) {
        float v0 = (L0[qq] + b2v0) * it;
        float v1 = (c < 4) ? (L1[qq] + b2v1) * it : -1e30f;
        float mx = red16max(fmaxf(v0, v1));
        float e0 = __expf(v0 - mx);
        float e1 = (c < 4) ? __expf(v1 - mx) : 0.f;
        float ssum = red16(e0 + e1);
        float inv = 1.f / ssum;
        buf[w][4 * g16 + qq][c] = f2bf(e0 * inv);
        buf[w][4 * g16 + qq][16 + c] = f2bf(e1 * inv);
    }
    // stage 3: pv = P @ anchors_emb, then LN2
    short8 A3 = *(const short8*)&buf[w][c][g16 * 8];
    f32x4 pv[8];
#pragma unroll
    for (int nt = 0; nt < 8; nt++) {
        const short8 B3 = *(const short8*)&anchS[nt * 16 + c][g16 * 8];
        f32x4 zz = {0.f, 0.f, 0.f, 0.f};
        pv[nt] = mfma16(A3, B3, zz);
    }
    float g2v[8], b2gv[8];
#pragma unroll
    for (int t = 0; t < 8; t++) { g2v[t] = g2[t * 16 + c]; b2gv[t] = bb2[t * 16 + c]; }
#pragma unroll
    for (int qq = 0; qq < 4; qq++) {
        float ps = 0.f, psq = 0.f;
#pragma unroll
        for (int t = 0; t < 8; t++) { float x = pv[t][qq]; ps += x; psq += x * x; }
        float s = red16(ps), sq = red16(psq);
        float mean = s * (1.f / 128.f);
        float var = sq * (1.f / 128.f) - mean * mean;
        float r = 1.f / sqrtf(var + 1e-5f);
        size_t base = (size_t)(item0 + 4 * g16 + qq) * 128;
#pragma unroll
        for (int t = 0; t < 8; t++) {
            float y = (pv[t][qq] - mean) * r * g2v[t] + b2gv[t];
            pvbf[base + t * 16 + c] = f2bf(y);
        }
    }
}

// ---------- gi_all[512*50][384] = gather(iv/pv)[sess] @ W_ih^T + b_ih (bf16 out) ----------
__global__ __launch_bounds__(256) void k_gi(const int* __restrict__ sess,
                                            const u16* __restrict__ ivbf,
                                            const u16* __restrict__ pvbf,
                                            const u16* __restrict__ wbf,
                                            const float* __restrict__ bih,
                                            u16* __restrict__ gi) {
    int w = threadIdx.x >> 6, l = threadIdx.x & 63;
    int mt = blockIdx.x * 4 + w;
    int r = mt * 16 + (l & 15);
    int s = r / 50, t = r - s * 50;
    int idx = sess[(s & 255) * 50 + t];
    const u16* srcb = (s < 256) ? ivbf : pvbf;
    int ko = (l >> 4) * 8;
    const short8 Z8 = {0, 0, 0, 0, 0, 0, 0, 0};
    short8 A[4];
    if (idx == 0) {
#pragma unroll
        for (int kb = 0; kb < 4; kb++) A[kb] = Z8;
    } else {
        const u16* rp = srcb + (size_t)(idx - 1) * 128 + ko;
#pragma unroll
        for (int kb = 0; kb < 4; kb++) A[kb] = *(const short8*)(rp + kb * 32);
    }
    int rowb = mt * 16 + (l >> 4) * 4;
    for (int nt = 0; nt < 24; nt++) {
        int gcol = nt * 16 + (l & 15);
        const u16* wp = wbf + gcol * 128 + ko;
        f32x4 acc = {0.f, 0.f, 0.f, 0.f};
#pragma unroll
        for (int kb = 0; kb < 4; kb++)
            acc = mfma16(A[kb], *(const short8*)(wp + kb * 32), acc);
        float bias = bih[gcol];
#pragma unroll
        for (int q = 0; q < 4; q++)
            gi[(size_t)(rowb + q) * 384 + gcol] = f2bf(acc[q] + bias);
    }
}

// ---------- GRU: 256 blocks x 2 seqs (b, b+256 share lengths[b]); W_hh bf16 in
// LDS. R9: hipcc won't keep a 128-VGPR weight array resident -> L2 re-stream.
// R10: MFMA version = 32 blocks = 12.5% of CUs -> worse. This version: all 256
// CUs, weights in LDS (swizzled), gi prefetched one step ahead.
__global__ __launch_bounds__(384, 1) void k_gru(const u16* __restrict__ gibf,
                                                const u16* __restrict__ whhbf,
                                                const float* __restrict__ bhh,
                                                const int* __restrict__ lengths,
                                                const float* __restrict__ g3,
                                                const float* __restrict__ b3,
                                                const float* __restrict__ g4,
                                                const float* __restrict__ b4,
                                                u32* __restrict__ htbf) {
    __shared__ u16 whhS[49152];                  // 96 KB, row-swizzled
    __shared__ __align__(16) float hA[2][128], hB[2][128];
    __shared__ float rA[128], zA[128], hnA[128], inA[128];
    __shared__ float rB[128], zB[128], hnB[128], inB[128];
    int g = threadIdx.x, b = blockIdx.x;
    // stage W_hh bf16 -> LDS, swizzle idx ^= ((row&15)<<3) (same XOR on read)
    for (int e8 = g * 8; e8 < 49152; e8 += 3072) {
        uint4 v = *(const uint4*)&whhbf[e8];
        *(uint4*)&whhS[e8 ^ (((e8 >> 7) & 15) << 3)] = v;
    }
    float bh = bhh[g];
    if (g < 128) { hA[0][g] = 0.f; hB[0][g] = 0.f; }
    int len = lengths[b];
    const u16* giA = gibf + (size_t)b * 50 * 384 + g;
    const u16* giB = gibf + (size_t)(b + 256) * 50 * 384 + g;
    int xo = (g & 15) << 3;
    const u16* wrow = &whhS[g * 128];
    float ga = bf2f(giA[0]), gb = bf2f(giB[0]);   // prefetch t=0
    __syncthreads();
    int par = 0;
    for (int t = 0; t < len; t++) {
        // prefetch next step's gi (hidden under the dot-product chain)
        float ga_n = 0.f, gb_n = 0.f;
        if (t + 1 < len) {
            ga_n = bf2f(giA[(t + 1) * 384]);
            gb_n = bf2f(giB[(t + 1) * 384]);
        }
        float aA = bh, aB = bh;
#pragma unroll
        for (int k = 0; k < 16; k++) {
            uint4 wv = *(const uint4*)&wrow[(k * 8) ^ xo];
            float4 w0, w1; unp8(wv, w0, w1);
            const float4* hap = (const float4*)&hA[par][k * 8];
            const float4* hbp = (const float4*)&hB[par][k * 8];
            float4 ha0 = hap[0], ha1 = hap[1];
            float4 hb0 = hbp[0], hb1 = hbp[1];
            aA += dot4(w0, ha0) + dot4(w1, ha1);
            aB += dot4(w0, hb0) + dot4(w1, hb1);
        }
        if (g < 128) {
            rA[g] = 1.f / (1.f + __expf(-(ga + aA)));
            rB[g] = 1.f / (1.f + __expf(-(gb + aB)));
        } else if (g < 256) {
            zA[g - 128] = 1.f / (1.f + __expf(-(ga + aA)));
            zB[g - 128] = 1.f / (1.f + __expf(-(gb + aB)));
        } else {
            inA[g - 256] = ga; hnA[g - 256] = aA;
            inB[g - 256] = gb; hnB[g - 256] = aB;
        }
        __syncthreads();
        if (g < 128) {
            float narg = inA[g] + rA[g] * hnA[g];
            float e2 = __expf(2.f * narg);
            float n = 1.f - 2.f / (e2 + 1.f);    // tanh, saturation-safe
            hA[par ^ 1][g] = (1.f - zA[g]) * n + zA[g] * hA[par][g];
        } else if (g < 256) {
            int d = g - 128;
            float narg = inB[d] + rB[d] * hnB[d];
            float e2 = __expf(2.f * narg);
            float n = 1.f - 2.f / (e2 + 1.f);
            hB[par ^ 1][d] = (1.f - zB[d]) * n + zB[d] * hB[par][d];
        }
        __syncthreads();
        par ^= 1; ga = ga_n; gb = gb_n;
    }
    int w = g >> 6, l = g & 63;
    if (w == 0) {
        float2 v = *(const float2*)&hA[par][2 * l];
        float s = wred(v.x + v.y), q = wred(v.x * v.x + v.y * v.y);
        float mean = s * (1.f / 128.f), var = q * (1.f / 128.f) - mean * mean;
        float r = 1.f / sqrtf(var + 1e-5f);
        float2 gg = *(const float2*)(g3 + 2 * l), bg = *(const float2*)(b3 + 2 * l);
        float y0 = (v.x - mean) * r * gg.x + bg.x;
        float y1 = (v.y - mean) * r * gg.y + bg.y;
        htbf[(size_t)b * 64 + l] = pack2(y0, y1);
    } else if (w == 1) {
        float2 v = *(const float2*)&hB[par][2 * l];
        float s = wred(v.x + v.y), q = wred(v.x * v.x + v.y * v.y);
        float mean = s * (1.f / 128.f), var = q * (1.f / 128.f) - mean * mean;
        float r = 1.f / sqrtf(var + 1e-5f);
        float2 gg = *(const float2*)(g4 + 2 * l), bg = *(const float2*)(b4 + 2 * l);
        float y0 = (v.x - mean) * r * gg.x + bg.x;
        float y1 = (v.y - mean) * r * gg.y + bg.y;
        htbf[(size_t)(b + 256) * 64 + l] = pack2(y0, y1);
    }
}

// ---------- scores: BM=256(all) x BN=64/block, bf16 MFMA, 3 outputs ----------
__global__ __launch_bounds__(256) void k_scores(const u16* __restrict__ htbf,
                                                const u16* __restrict__ ivbf,
                                                const u16* __restrict__ pvbf,
                                                const float* __restrict__ a1,
                                                const float* __restrict__ a2,
                                                float* __restrict__ out) {
    int w = threadIdx.x >> 6, l = threadIdx.x & 63;
    int n0 = blockIdx.x * 64;
    int ko = (l >> 4) * 8;
    short8 Ai[4][4], Ap[4][4];
#pragma unroll
    for (int mi = 0; mi < 4; mi++) {
        int row = w * 64 + mi * 16 + (l & 15);
        const u16* pi = htbf + row * 128 + ko;
        const u16* pp = htbf + (row + 256) * 128 + ko;
#pragma unroll
        for (int kb = 0; kb < 4; kb++) {
            Ai[mi][kb] = *(const short8*)(pi + kb * 32);
            Ap[mi][kb] = *(const short8*)(pp + kb * 32);
        }
    }
    float s1 = sigf(a1[0]), s2 = sigf(a2[0]);
    float* sc = out;
    float* si = out + (size_t)20480000;
    float* sp = out + (size_t)40960000;
    for (int nt = 0; nt < 4; nt++) {
        int col = n0 + nt * 16 + (l & 15);
        const u16* bi = ivbf + (size_t)col * 128 + ko;
        const u16* bp = pvbf + (size_t)col * 128 + ko;
        short8 Bi[4], Bp[4];
#pragma unroll
        for (int kb = 0; kb < 4; kb++) {
            Bi[kb] = *(const short8*)(bi + kb * 32);
            Bp[kb] = *(const short8*)(bp + kb * 32);
        }
#pragma unroll
        for (int mi = 0; mi < 4; mi++) {
            f32x4 ai = {0.f, 0.f, 0.f, 0.f}, ap = {0.f, 0.f, 0.f, 0.f};
#pragma unroll
            for (int kb = 0; kb < 4; kb++) {
                ai = mfma16(Ai[mi][kb], Bi[kb], ai);
                ap = mfma16(Ap[mi][kb], Bp[kb], ap);
            }
            int rowb = w * 64 + mi * 16 + (l >> 4) * 4;
#pragma unroll
            for (int q = 0; q < 4; q++) {
                size_t o = (size_t)(rowb + q) * 80000 + col;
                float vi = ai[q], vp = ap[q];
                __builtin_nontemporal_store(vi, si + o);
                __builtin_nontemporal_store(vp, sp + o);
                __builtin_nontemporal_store(s1 * vi + s2 * vp, sc + o);
            }
        }
    }
}

extern "C" void kernel_launch(void* const* d_in, const int* in_sizes, int n_in,
                              void* d_out, int out_size, void* d_ws, size_t ws_size,
                              hipStream_t stream) {
    (void)in_sizes; (void)n_in; (void)out_size; (void)ws_size;
    const int*   sess    = (const int*)d_in[0];
    const int*   lengths = (const int*)d_in[1];
    const float* tau     = (const float*)d_in[4];
    const int*   adj     = (const int*)d_in[5];
    const int*   anchors = (const int*)d_in[6];
    const float* emb     = (const float*)d_in[7];
    const float* W_ih    = (const float*)d_in[8];
    const float* W_hh    = (const float*)d_in[9];
    const float* b_ih    = (const float*)d_in[10];
    const float* b_hh    = (const float*)d_in[11];
    const float* W1      = (const float*)d_in[12];
    const float* b1      = (const float*)d_in[13];
    const float* W2      = (const float*)d_in[14];
    const float* b2      = (const float*)d_in[15];
    const float* a1      = (const float*)d_in[16];
    const float* a2      = (const float*)d_in[17];
    const float* ln1g = (const float*)d_in[18];
    const float* ln1b = (const float*)d_in[19];
    const float* ln2g = (const float*)d_in[20];
    const float* ln2b = (const float*)d_in[21];
    const float* ln3g = (const float*)d_in[22];
    const float* ln3b = (const float*)d_in[23];
    const float* ln4g = (const float*)d_in[24];
    const float* ln4b = (const float*)d_in[25];

    float* out = (float*)d_out;
    // d_out doubles as scratch; all scratch dead before k_scores overwrites it.
    u32* o_xn = (u32*)out;                   // packed bf16 xn (5.12M u32)
    u32* o_o1 = (u32*)(out + SLOT);          // packed bf16 hop-1 out
    u16* o_gi = (u16*)(out + 2 * SLOT);      // gi_all bf16 (9.83M u16)

    u16* ws16   = (u16*)d_ws;        // ~41.4 MB
    u16* ivbf   = ws16;                      // 10,240,000
    u16* pvbf   = ws16 + 10240000;           // 10,240,000
    u16* wihbf  = ws16 + 20480000;           // 49,152
    u16* htbf   = ws16 + 20529152;           // 65,536
    u16* w1bf   = ws16 + 20594688;           // 16,384
    u16* w2bf   = ws16 + 20611072;           // 4,096
    u16* whhbf  = ws16 + 20615168;           // 49,152

    k_cvtnorm<<<5464, 256, 0, stream>>>(W_ih, W1, W2, W_hh, wihbf, w1bf, w2bf,
                                        whhbf, emb + 128, o_xn);
    k_routeb<<<5000, 256, 0, stream>>>(o_xn, adj, o_o1);
    k_route2lnb<<<5000, 256, 0, stream>>>(o_o1, emb + 128, adj, ln1g, ln1b, (u32*)ivbf);
    k_popm<<<1250, 256, 0, stream>>>(ivbf, w1bf, b1, w2bf, b2, tau, anchors,
                                     ln2g, ln2b, pvbf);
    k_gi<<<400, 256, 0, stream>>>(sess, ivbf, pvbf, wihbf, b_ih, o_gi);
    k_gru<<<256, 384, 0, stream>>>(o_gi, whhbf, b_hh, lengths, ln3g, ln3b, ln4g, ln4b,
                                   (u32*)htbf);
    k_scores<<<1250, 256, 0, stream>>>(htbf, ivbf, pvbf, a1, a2, out);
}